// Round 11
// baseline (180.205 us; speedup 1.0000x reference)
//
#include <hip/hip_runtime.h>
#include <stdint.h>

typedef unsigned short u16;
typedef short short8 __attribute__((ext_vector_type(8)));
typedef float f32x4 __attribute__((ext_vector_type(4)));
typedef float f32x16 __attribute__((ext_vector_type(16)));
typedef float f32x2 __attribute__((ext_vector_type(2)));

// ---------- helpers ----------
__device__ __forceinline__ u16 f2bf_fast(float f) {
  union { float f; uint32_t u; } x;
  x.f = f;
  return (u16)((x.u + 0x8000u) >> 16);
}

__device__ __forceinline__ uint32_t pack2bf(float lo, float hi) {
  union { float f; uint32_t u; } a, b;
  a.f = lo; b.f = hi;
  return __builtin_amdgcn_perm(b.u + 0x8000u, a.u + 0x8000u, 0x07060302u);
}

__device__ __forceinline__ float bf2f(uint32_t u) {
  union { uint32_t u; float f; } x;
  x.u = u << 16;
  return x.f;
}

// v_cvt_pk_bf16_f32: D = {bf16(lo), bf16(hi)} (RNE). No builtin on gfx950.
__device__ __forceinline__ uint32_t cvtpk(float lo, float hi) {
  uint32_t r;
  asm("v_cvt_pk_bf16_f32 %0, %1, %2" : "=v"(r) : "v"(lo), "v"(hi));
  return r;
}

// v_permlane32_swap_b32: a.row1 <-> b.row0 (rows = 32-lane halves).
__device__ __forceinline__ void permswap(uint32_t& a, uint32_t& b) {
  asm("v_permlane32_swap_b32 %0, %1" : "+v"(a), "+v"(b));
}

__device__ __forceinline__ void gload_lds16(const void* g, void* l) {
  __builtin_amdgcn_global_load_lds(
      (const __attribute__((address_space(1))) void*)g,
      (__attribute__((address_space(3))) void*)l, 16, 0, 0);
}

__device__ __forceinline__ f32x4 mfma16(short8 a, short8 b, f32x4 c) {
  return __builtin_amdgcn_mfma_f32_16x16x32_bf16(a, b, c, 0, 0, 0);
}

__device__ __forceinline__ f32x16 mfma32(short8 a, short8 b, f32x16 c) {
  return __builtin_amdgcn_mfma_f32_32x32x16_bf16(a, b, c, 0, 0, 0);
}

#define QSCALE 0.18033688011112042f

// ---------- pack fp32 -> bf16 P32 fragment layout ----------
// P32: pack[((rt*32+kc)*64+ln)*8+j] = M[rt*16+(ln&15)][kc*32+(ln>>4)*8+j]
// rt 0..255 -> x (4096x1024) into xp; rt 256..511 -> [Wq;Wk;Wv;Wo] into wp.
__global__ void pack_all(const float* __restrict__ x, const float* __restrict__ wq,
                         const float* __restrict__ wk, const float* __restrict__ wv,
                         const float* __restrict__ wo, u16* __restrict__ xp,
                         u16* __restrict__ wp) {
  const int gi = blockIdx.x * 256 + threadIdx.x;  // granule id, 0..1048575
  const int lane = gi & 63;
  const int kc = (gi >> 6) & 31;
  const int rt = gi >> 11;  // row tile 0..511
  const int col = kc * 32 + (lane >> 4) * 8;
  const float* src;
  int row;
  if (rt < 256) {
    src = x;
    row = rt * 16 + (lane & 15);
  } else {
    const int wti = rt - 256;             // 0..255
    const int widx = wti >> 6;            // which weight
    src = (widx == 0) ? wq : (widx == 1) ? wk : (widx == 2) ? wv : wo;
    row = (wti & 63) * 16 + (lane & 15);
  }
  const float4* p = (const float4*)(src + (size_t)row * 1024 + col);
  const float4 v0 = p[0], v1 = p[1];
  uint4 o;
  o.x = pack2bf(v0.x, v0.y);
  o.y = pack2bf(v0.z, v0.w);
  o.z = pack2bf(v1.x, v1.y);
  o.w = pack2bf(v1.z, v1.w);
  u16* dst = (rt < 256) ? xp : wp;
  const int og = (rt < 256) ? gi : gi - 524288;
  ((uint4*)dst)[og] = o;
}

// ---------- LDS-staged 128x128 projection GEMM, min-2-phase dbuf ----------
// Loop identical to the 43.7/45.0-us-measured R3/R9 body + R10 coalesced
// epilogue (C via wave-private LDS -> 128B-row stores; WRITE_SIZE fixed).
// works 0..511:  QK: C = x @ [Wq|Wk]^T, block (bm2 0..31, bn2 0..15).
// works 512..767: V: C = Wv @ x^T,      block (bm2 0..7,  bn2 0..31).
__global__ __launch_bounds__(256, 3) void proj_qkv(
    const u16* __restrict__ xp, const u16* __restrict__ wp,
    const float* __restrict__ bq, const float* __restrict__ bk,
    const float* __restrict__ bv, u16* __restrict__ qw, u16* __restrict__ kw,
    u16* __restrict__ vw) {
  __shared__ __align__(16) u16 As[8192];   // 2 bufs x (8 row-tiles x 1 kc)
  __shared__ __align__(16) u16 Bs[8192];
  const int tid = threadIdx.x, lane = tid & 63, w = tid >> 6;
  const int quad = lane >> 4, l15 = lane & 15;

  // bijective XCD-chunked swizzle: 768 blocks, 96 per XCD
  const int bid = blockIdx.x;
  const int work = (bid & 7) * 96 + (bid >> 3);
  const bool isQK = work < 512;
  int at0, bt0, bm2, bn2;
  const u16 *Ap, *Bp;
  if (isQK) {
    bm2 = work >> 4; bn2 = work & 15;          // bm-major: B panel L2-resident
    Ap = xp; at0 = bm2 * 8;
    Bp = wp; bt0 = bn2 * 8;                    // Wq|Wk tiles 0..127
  } else {
    const int h = work - 512;
    bm2 = h >> 5; bn2 = h & 31;
    Ap = wp; at0 = 128 + bm2 * 8;              // Wv tiles 128..191
    Bp = xp; bt0 = bn2 * 8;                    // x row-tiles (seq)
  }
  const int wr = w >> 1, wc = w & 1;
  const int bm = bm2 * 2 + wr, bn = bn2 * 2 + wc;  // 64-row/col units

  // stage one kc (32-deep K slice): 16 granules, 4 per wave
  auto stage = [&](int kc, int buf) {
#pragma unroll
    for (int i = 0; i < 4; ++i) {
      const int g = w * 4 + i;                 // 0..15
      const int t = g & 7;
      const u16* src = (g < 8)
          ? (Ap + (((at0 + t) << 5) + kc) * 512 + lane * 8)
          : (Bp + (((bt0 + t) << 5) + kc) * 512 + lane * 8);
      u16* dst = ((g < 8) ? As : Bs) + (buf * 8 + t) * 512 + lane * 8;
      gload_lds16(src, dst);
    }
  };

  f32x4 acc[4][4] = {};

  stage(0, 0);
  __syncthreads();

  for (int kc = 0; kc < 32; ++kc) {
    const int cur = kc & 1;
    if (kc < 31) stage(kc + 1, cur ^ 1);

    const u16* Ab = As + cur * 4096;
    const u16* Bb = Bs + cur * 4096;
    short8 af[4], bf[4];
#pragma unroll
    for (int mt = 0; mt < 4; ++mt)
      af[mt] = *(const short8*)&Ab[((wr * 4 + mt) * 64 + lane) * 8];
#pragma unroll
    for (int nt = 0; nt < 4; ++nt)
      bf[nt] = *(const short8*)&Bb[((wc * 4 + nt) * 64 + lane) * 8];

#pragma unroll
    for (int mt = 0; mt < 4; ++mt)
#pragma unroll
      for (int nt = 0; nt < 4; ++nt)
        acc[mt][nt] = mfma16(af[mt], bf[nt], acc[mt][nt]);
    __syncthreads();   // drains vmcnt (next buf staged) + readers done
  }

  // ---- coalesced epilogue: C -> wave-private LDS (bf16) -> 128B rows ----
  u16* tw = ((w < 2) ? As : Bs) + (w & 1) * 4096;
#pragma unroll
  for (int nt = 0; nt < 4; ++nt) {
    const int n = bn * 64 + nt * 16 + l15;
    float ba = 0.f, sc = 1.f;
    if (isQK) {
      if (bn < 16) { ba = bq[n] * QSCALE; sc = QSCALE; }
      else          ba = bk[n - 1024];
    }
#pragma unroll
    for (int mt = 0; mt < 4; ++mt)
#pragma unroll
      for (int r = 0; r < 4; ++r) {
        const int m = bm * 64 + mt * 16 + quad * 4 + r;
        const float v = isQK ? (acc[mt][nt][r] * sc + ba)
                             : (acc[mt][nt][r] + bv[m]);
        tw[(mt * 16 + quad * 4 + r) * 64 + nt * 16 + l15] = f2bf_fast(v);
      }
  }
  const int rr = lane >> 3, ch = lane & 7;   // 8 rows x 8 chunks of 16B
  if (isQK) {
    const bool isQ = (bn < 16);
    u16* op = isQ ? qw : kw;
    const int hh = isQ ? bn : bn - 16;
#pragma unroll
    for (int p = 0; p < 8; ++p) {
      const int row = p * 8 + rr;            // m_local
      const int m = bm * 64 + row;
      const int b = m >> 11, s = m & 2047;
      const uint4 val = *(const uint4*)&tw[row * 64 + ch * 8];
      *(uint4*)(op + ((size_t)((b * 16 + hh) * 2048 + s)) * 64 + ch * 8) = val;
    }
  } else {
    const int nb = bn * 64;
    const int b = nb >> 11, s = nb & 2047;   // wave's 64 seq cols, same b
#pragma unroll
    for (int p = 0; p < 8; ++p) {
      const int row = p * 8 + rr;            // m_local (dout)
      const int m = bm * 64 + row;
      const uint4 val = *(const uint4*)&tw[row * 64 + ch * 8];
      *(uint4*)(vw + ((size_t)(b * 1024 + m)) * 2048 + s + ch * 8) = val;
    }
  }
}

// ---------- flash attention: in-block K-split, 8 waves (R4 verified) ----------
// NEW (R11): XCD-chunked block remap — each XCD owns 4 heads x 16 q-tiles,
// so its KV working set is 4 x 512KB = 2MB, L2-resident (was all-32-heads
// = 16MB >> 4MB L2 -> HBM-latency staging, FETCH 69.7MB vs 24MB ideal).
// Block = 512 threads = waves (kh 0..1) x (qg 0..3). Wave (kh,qg) computes
// q-rows [qg*32,qg*32+32) over K-tiles [kh*16,kh*16+16). End: kh=1 pushes
// partial (ot,l) via LDS, kh=0 combines, normalizes, writes awp.
// LDS 80 KB -> 2 blocks/CU x 8 waves = 16 waves/CU (4/SIMD).
__global__ __launch_bounds__(512, 4) void attn_kernel(
    const u16* __restrict__ Q, const u16* __restrict__ Kt,
    const u16* __restrict__ Vt, u16* __restrict__ awp) {
  __shared__ __align__(16) u16 Sm[40960];  // 80 KB
  const int tid = threadIdx.x, lane = tid & 63, w = tid >> 6;  // w 0..7
  const int l31 = lane & 31, hi = lane >> 5, l7 = lane & 7;
  const int kh = w >> 2, qg = w & 3;

  // bijective XCD chunk: 512 blocks, 64 per XCD -> 4 heads per XCD
  const int bid = blockIdx.y * 16 + blockIdx.x;
  const int work = (bid & 7) * 64 + (bid >> 3);
  const int qt = work & 15;    // 0..15
  const int bh = work >> 4;    // 0..31

  const char* Qb = (const char*)(Q + ((size_t)bh * 2048 + qt * 128) * 64);
  const char* Kb = (const char*)(Kt + (size_t)bh * 2048 * 64);
  const char* Vb = (const char*)(Vt + (size_t)bh * 64 * 2048);

  // K/V buffers: Sm + (buf*2 + half)*8192 u16 (K tile 4096 u16, V next 4096)
  auto stageKV = [&](int j, int buf) {
#pragma unroll
    for (int h = 0; h < 2; ++h) {
      const int kt = h * 16 + j;
      u16* Kl = Sm + (buf * 2 + h) * 8192;
      u16* Vl = Kl + 4096;
      const int G = w * 64 + lane;     // 0..511
      const int r = G >> 3, sl = G & 7;
      gload_lds16(Kb + (size_t)(kt * 64 + r) * 128 + ((sl ^ (r & 7)) * 16),
                  &Kl[G * 8]);
      gload_lds16(Vb + (size_t)r * 4096 + kt * 128 + ((sl ^ (r & 7)) * 16),
                  &Vl[G * 8]);
    }
  };

  u16* Qs = Sm + 32768;  // 128 rows x 64 u16
#pragma unroll
  for (int i = 0; i < 2; ++i) {
    const int G = (w * 2 + i) * 64 + lane;   // 0..1023
    const int row = G >> 3, sl = G & 7;
    gload_lds16(Qb + (size_t)row * 128 + ((sl ^ (row & 7)) * 16), &Qs[G * 8]);
  }
  stageKV(0, 0);
  __syncthreads();

  // Q fragment (B-operand of 32x32x16): q = l31, d = ds*16 + hi*8 + j
  short8 aq[4];
#pragma unroll
  for (int ds = 0; ds < 4; ++ds)
    aq[ds] = *(const short8*)&Qs[(qg * 32 + l31) * 64 + (((ds << 1) + hi) ^ l7) * 8];
  // Qs is never overwritten during the loop -> no barrier needed here.

  f32x16 ot[2] = {};   // O^T acc: dt in {0,1}, d = dt*32 + (reg&3)+8*(reg>>2)+4*hi
  f32x2 l2 = {0.f, 0.f};

  for (int j = 0; j < 16; ++j) {
    const int buf = j & 1;
    if (j < 15) stageKV(j + 1, buf ^ 1);
    const u16* Kl = Sm + (buf * 2 + kh) * 8192;
    const u16* Vl = Kl + 4096;

#pragma unroll
    for (int t = 0; t < 2; ++t) {  // two 32-k S^T tiles per 64-k LDS tile
      f32x16 st = {};
      __builtin_amdgcn_s_setprio(1);
#pragma unroll
      for (int ds = 0; ds < 4; ++ds) {
        short8 kf = *(const short8*)&Kl[(t * 32 + l31) * 64 +
                                        (((ds << 1) + hi) ^ l7) * 8];
        st = mfma32(kf, aq[ds], st);
      }
      __builtin_amdgcn_s_setprio(0);
      float e[16];
#pragma unroll
      for (int i = 0; i < 16; ++i) e[i] = __builtin_amdgcn_exp2f(st[i]);
#pragma unroll
      for (int i = 0; i < 8; ++i) l2 += (f32x2){e[2 * i], e[2 * i + 1]};

      // pack to PV B-fragments: pairing (e0,e1)x(e4,e5) etc per T12
      uint32_t p01 = cvtpk(e[0], e[1]),   p23 = cvtpk(e[2], e[3]);
      uint32_t p45 = cvtpk(e[4], e[5]),   p67 = cvtpk(e[6], e[7]);
      uint32_t p89 = cvtpk(e[8], e[9]),   pAB = cvtpk(e[10], e[11]);
      uint32_t pCD = cvtpk(e[12], e[13]), pEF = cvtpk(e[14], e[15]);
      permswap(p01, p45);  // -> ksub0 w0, w2
      permswap(p23, p67);  // -> ksub0 w1, w3
      permswap(p89, pCD);  // -> ksub1 w0, w2
      permswap(pAB, pEF);  // -> ksub1 w1, w3
      union { uint32_t u[4]; short8 s; } b0, b1;
      b0.u[0] = p01; b0.u[1] = p23; b0.u[2] = p45; b0.u[3] = p67;
      b1.u[0] = p89; b1.u[1] = pAB; b1.u[2] = pCD; b1.u[3] = pEF;

      __builtin_amdgcn_s_setprio(1);
#pragma unroll
      for (int dt = 0; dt < 2; ++dt) {
#pragma unroll
        for (int s2 = 0; s2 < 2; ++s2) {
          short8 vf = *(const short8*)&Vl[(dt * 32 + l31) * 64 +
                                          ((((t * 2 + s2) << 1) + hi) ^ l7) * 8];
          ot[dt] = mfma32(vf, s2 ? b1.s : b0.s, ot[dt]);
        }
      }
      __builtin_amdgcn_s_setprio(0);
    }
    if (j < 15) __syncthreads();
  }

  // l partial for this wave's kt-range, per q=l31
  float l = l2.x + l2.y;
  l += __shfl_xor(l, 32);

  // ---- in-block combine: kh=1 -> LDS -> kh=0 adds, normalizes, writes ----
  __syncthreads();   // all compute done before reusing Sm
  float* fb = (float*)Sm;  // slot per (qg,lane): 34 floats, b64 stride-34
  if (kh == 1) {
    float* p = fb + (qg * 64 + lane) * 34;
#pragma unroll
    for (int i = 0; i < 8; ++i) {
      *(f32x2*)(p + 2 * i)      = (f32x2){ot[0][2 * i], ot[0][2 * i + 1]};
      *(f32x2*)(p + 16 + 2 * i) = (f32x2){ot[1][2 * i], ot[1][2 * i + 1]};
    }
    p[32] = l;
  }
  __syncthreads();
  if (kh == 0) {
    const float* p = fb + (qg * 64 + lane) * 34;
#pragma unroll
    for (int i = 0; i < 16; ++i) ot[0][i] += p[i];
#pragma unroll
    for (int i = 0; i < 16; ++i) ot[1][i] += p[16 + i];
    l += p[32];
    const float inv = __builtin_amdgcn_rcpf(l);

    const int b = bh >> 4, h = bh & 15;
    const int rt = b * 128 + qt * 8 + qg * 2 + (l31 >> 4);  // row = rt*16+(lane&15)
#pragma unroll
    for (int dt = 0; dt < 2; ++dt) {
      const int kc = h * 2 + dt;
#pragma unroll
      for (int g = 0; g < 4; ++g) {  // reg group: d = dt*32+(reg&3)+8*g+4*hi
        const int ln = (lane & 15) + 16 * g;
        uint2 ov;
        ov.x = cvtpk(ot[dt][4 * g + 0] * inv, ot[dt][4 * g + 1] * inv);
        ov.y = cvtpk(ot[dt][4 * g + 2] * inv, ot[dt][4 * g + 3] * inv);
        *(uint2*)(awp + ((size_t)((rt * 32 + kc) * 64 + ln)) * 8 + hi * 4) = ov;
      }
    }
  }
}

// ---------- LDS-staged out projection, min-2-phase dbuf ----------
// C[4096,1024] f32 = aw @ Wo^T + bo. 128x128 tile, 512 threads (8 waves
// of 64x32), BK=32 double-buffered.
__global__ __launch_bounds__(512, 2) void out_proj(const u16* __restrict__ awp,
                                                   const u16* __restrict__ wp,
                                                   const float* __restrict__ bo,
                                                   float* __restrict__ out) {
  __shared__ __align__(16) u16 As[8192];
  __shared__ __align__(16) u16 Bs[8192];
  const int tid = threadIdx.x, lane = tid & 63, w = tid >> 6;  // w 0..7
  const int quad = lane >> 4, l15 = lane & 15;

  const int bid = blockIdx.x;                    // 0..255
  const int work = (bid & 7) * 32 + (bid >> 3);  // bijective XCD chunk
  const int bm2 = work >> 3, bn2 = work & 7;     // 32 x 8 grid
  const int at0 = bm2 * 8, bt0 = 192 + bn2 * 8;  // Wo = wp tiles 192..255
  const int wr = w >> 2, wc = w & 3;             // wave tile 64x32

  auto stage = [&](int kc, int buf) {
#pragma unroll
    for (int i = 0; i < 2; ++i) {
      const int g = w * 2 + i;                   // 0..15
      const int t = g & 7;
      const u16* src = (g < 8)
          ? (awp + (((at0 + t) << 5) + kc) * 512 + lane * 8)
          : (wp + (((bt0 + t) << 5) + kc) * 512 + lane * 8);
      u16* dst = ((g < 8) ? As : Bs) + (buf * 8 + t) * 512 + lane * 8;
      gload_lds16(src, dst);
    }
  };

  f32x4 acc[4][2] = {};

  stage(0, 0);
  __syncthreads();

  for (int kc = 0; kc < 32; ++kc) {
    const int cur = kc & 1;
    if (kc < 31) stage(kc + 1, cur ^ 1);

    const u16* Ab = As + cur * 4096;
    const u16* Bb = Bs + cur * 4096;
    short8 af[4], bf[2];
#pragma unroll
    for (int mt = 0; mt < 4; ++mt)
      af[mt] = *(const short8*)&Ab[((wr * 4 + mt) * 64 + lane) * 8];
#pragma unroll
    for (int nt = 0; nt < 2; ++nt)
      bf[nt] = *(const short8*)&Bb[((wc * 2 + nt) * 64 + lane) * 8];

#pragma unroll
    for (int mt = 0; mt < 4; ++mt)
#pragma unroll
      for (int nt = 0; nt < 2; ++nt)
        acc[mt][nt] = mfma16(af[mt], bf[nt], acc[mt][nt]);
    __syncthreads();
  }

#pragma unroll
  for (int nt = 0; nt < 2; ++nt) {
    const int n = bn2 * 128 + wc * 32 + nt * 16 + l15;
    const float bb = bo[n];
#pragma unroll
    for (int mt = 0; mt < 4; ++mt)
#pragma unroll
      for (int r = 0; r < 4; ++r) {
        const int m = bm2 * 128 + wr * 64 + mt * 16 + quad * 4 + r;
        out[(size_t)m * 1024 + n] = acc[mt][nt][r] + bb;
      }
  }
}

// ---------- launch ----------
extern "C" void kernel_launch(void* const* d_in, const int* in_sizes, int n_in,
                              void* d_out, int out_size, void* d_ws, size_t ws_size,
                              hipStream_t stream) {
  const float* x  = (const float*)d_in[0];
  const float* Wq = (const float*)d_in[1];
  const float* bq = (const float*)d_in[2];
  const float* Wk = (const float*)d_in[3];
  const float* bk = (const float*)d_in[4];
  const float* Wv = (const float*)d_in[5];
  const float* bv = (const float*)d_in[6];
  const float* Wo = (const float*)d_in[7];
  const float* bo = (const float*)d_in[8];

  const size_t M4 = (size_t)4 * 1024 * 1024;
  u16* xp  = (u16*)d_ws;
  u16* wp  = xp + M4;        // packed [Wq;Wk;Wv;Wo]
  u16* qw  = wp + M4;
  u16* kw  = qw + M4;
  u16* vw  = kw + M4;
  u16* awp = vw + M4;

  pack_all<<<4096, 256, 0, stream>>>(x, Wq, Wk, Wv, Wo, xp, wp);

  proj_qkv<<<768, 256, 0, stream>>>(xp, wp, bq, bk, bv, qw, kw, vw);

  attn_kernel<<<dim3(16, 32), 512, 0, stream>>>(qw, kw, vw, awp);

  out_proj<<<256, 512, 0, stream>>>(awp, wp, bo, (float*)d_out);
}

// Round 12
// 174.203 us; speedup vs baseline: 1.0345x; 1.0345x over previous
//
#include <hip/hip_runtime.h>
#include <stdint.h>

typedef unsigned short u16;
typedef short short8 __attribute__((ext_vector_type(8)));
typedef float f32x4 __attribute__((ext_vector_type(4)));
typedef float f32x16 __attribute__((ext_vector_type(16)));
typedef float f32x2 __attribute__((ext_vector_type(2)));

// ---------- helpers ----------
__device__ __forceinline__ u16 f2bf_fast(float f) {
  union { float f; uint32_t u; } x;
  x.f = f;
  return (u16)((x.u + 0x8000u) >> 16);
}

__device__ __forceinline__ uint32_t pack2bf(float lo, float hi) {
  union { float f; uint32_t u; } a, b;
  a.f = lo; b.f = hi;
  return __builtin_amdgcn_perm(b.u + 0x8000u, a.u + 0x8000u, 0x07060302u);
}

__device__ __forceinline__ float bf2f(uint32_t u) {
  union { uint32_t u; float f; } x;
  x.u = u << 16;
  return x.f;
}

// v_cvt_pk_bf16_f32: D = {bf16(lo), bf16(hi)} (RNE). No builtin on gfx950.
__device__ __forceinline__ uint32_t cvtpk(float lo, float hi) {
  uint32_t r;
  asm("v_cvt_pk_bf16_f32 %0, %1, %2" : "=v"(r) : "v"(lo), "v"(hi));
  return r;
}

// v_permlane32_swap_b32: a.row1 <-> b.row0 (rows = 32-lane halves).
__device__ __forceinline__ void permswap(uint32_t& a, uint32_t& b) {
  asm("v_permlane32_swap_b32 %0, %1" : "+v"(a), "+v"(b));
}

__device__ __forceinline__ void gload_lds16(const void* g, void* l) {
  __builtin_amdgcn_global_load_lds(
      (const __attribute__((address_space(1))) void*)g,
      (__attribute__((address_space(3))) void*)l, 16, 0, 0);
}

__device__ __forceinline__ f32x4 mfma16(short8 a, short8 b, f32x4 c) {
  return __builtin_amdgcn_mfma_f32_16x16x32_bf16(a, b, c, 0, 0, 0);
}

__device__ __forceinline__ f32x16 mfma32(short8 a, short8 b, f32x16 c) {
  return __builtin_amdgcn_mfma_f32_32x32x16_bf16(a, b, c, 0, 0, 0);
}

#define QSCALE 0.18033688011112042f

// ---------- pack fp32 -> bf16 P32 fragment layout ----------
// P32: pack[((rt*32+kc)*64+ln)*8+j] = M[rt*16+(ln&15)][kc*32+(ln>>4)*8+j]
// rt 0..255 -> x (4096x1024) into xp; rt 256..511 -> [Wq;Wk;Wv;Wo] into wp.
__global__ void pack_all(const float* __restrict__ x, const float* __restrict__ wq,
                         const float* __restrict__ wk, const float* __restrict__ wv,
                         const float* __restrict__ wo, u16* __restrict__ xp,
                         u16* __restrict__ wp) {
  const int gi = blockIdx.x * 256 + threadIdx.x;  // granule id, 0..1048575
  const int lane = gi & 63;
  const int kc = (gi >> 6) & 31;
  const int rt = gi >> 11;  // row tile 0..511
  const int col = kc * 32 + (lane >> 4) * 8;
  const float* src;
  int row;
  if (rt < 256) {
    src = x;
    row = rt * 16 + (lane & 15);
  } else {
    const int wti = rt - 256;             // 0..255
    const int widx = wti >> 6;            // which weight
    src = (widx == 0) ? wq : (widx == 1) ? wk : (widx == 2) ? wv : wo;
    row = (wti & 63) * 16 + (lane & 15);
  }
  const float4* p = (const float4*)(src + (size_t)row * 1024 + col);
  const float4 v0 = p[0], v1 = p[1];
  uint4 o;
  o.x = pack2bf(v0.x, v0.y);
  o.y = pack2bf(v0.z, v0.w);
  o.z = pack2bf(v1.x, v1.y);
  o.w = pack2bf(v1.z, v1.w);
  u16* dst = (rt < 256) ? xp : wp;
  const int og = (rt < 256) ? gi : gi - 524288;
  ((uint4*)dst)[og] = o;
}

// ---------- LDS-staged 128x128 projection GEMM, min-2-phase dbuf ----------
// Loop identical to the 43.7/45.0-us-measured R3/R9 body + R10 coalesced
// epilogue (C via wave-private LDS -> 128B-row stores; WRITE_SIZE fixed).
// works 0..511:  QK: C = x @ [Wq|Wk]^T, block (bm2 0..31, bn2 0..15).
// works 512..767: V: C = Wv @ x^T,      block (bm2 0..7,  bn2 0..31).
__global__ __launch_bounds__(256, 3) void proj_qkv(
    const u16* __restrict__ xp, const u16* __restrict__ wp,
    const float* __restrict__ bq, const float* __restrict__ bk,
    const float* __restrict__ bv, u16* __restrict__ qw, u16* __restrict__ kw,
    u16* __restrict__ vw) {
  __shared__ __align__(16) u16 As[8192];   // 2 bufs x (8 row-tiles x 1 kc)
  __shared__ __align__(16) u16 Bs[8192];
  const int tid = threadIdx.x, lane = tid & 63, w = tid >> 6;
  const int quad = lane >> 4, l15 = lane & 15;

  // bijective XCD-chunked swizzle: 768 blocks, 96 per XCD
  const int bid = blockIdx.x;
  const int work = (bid & 7) * 96 + (bid >> 3);
  const bool isQK = work < 512;
  int at0, bt0, bm2, bn2;
  const u16 *Ap, *Bp;
  if (isQK) {
    bm2 = work >> 4; bn2 = work & 15;          // bm-major: B panel L2-resident
    Ap = xp; at0 = bm2 * 8;
    Bp = wp; bt0 = bn2 * 8;                    // Wq|Wk tiles 0..127
  } else {
    const int h = work - 512;
    bm2 = h >> 5; bn2 = h & 31;
    Ap = wp; at0 = 128 + bm2 * 8;              // Wv tiles 128..191
    Bp = xp; bt0 = bn2 * 8;                    // x row-tiles (seq)
  }
  const int wr = w >> 1, wc = w & 1;
  const int bm = bm2 * 2 + wr, bn = bn2 * 2 + wc;  // 64-row/col units

  // stage one kc (32-deep K slice): 16 granules, 4 per wave
  auto stage = [&](int kc, int buf) {
#pragma unroll
    for (int i = 0; i < 4; ++i) {
      const int g = w * 4 + i;                 // 0..15
      const int t = g & 7;
      const u16* src = (g < 8)
          ? (Ap + (((at0 + t) << 5) + kc) * 512 + lane * 8)
          : (Bp + (((bt0 + t) << 5) + kc) * 512 + lane * 8);
      u16* dst = ((g < 8) ? As : Bs) + (buf * 8 + t) * 512 + lane * 8;
      gload_lds16(src, dst);
    }
  };

  f32x4 acc[4][4] = {};

  stage(0, 0);
  __syncthreads();

  for (int kc = 0; kc < 32; ++kc) {
    const int cur = kc & 1;
    if (kc < 31) stage(kc + 1, cur ^ 1);

    const u16* Ab = As + cur * 4096;
    const u16* Bb = Bs + cur * 4096;
    short8 af[4], bf[4];
#pragma unroll
    for (int mt = 0; mt < 4; ++mt)
      af[mt] = *(const short8*)&Ab[((wr * 4 + mt) * 64 + lane) * 8];
#pragma unroll
    for (int nt = 0; nt < 4; ++nt)
      bf[nt] = *(const short8*)&Bb[((wc * 4 + nt) * 64 + lane) * 8];

#pragma unroll
    for (int mt = 0; mt < 4; ++mt)
#pragma unroll
      for (int nt = 0; nt < 4; ++nt)
        acc[mt][nt] = mfma16(af[mt], bf[nt], acc[mt][nt]);
    __syncthreads();   // drains vmcnt (next buf staged) + readers done
  }

  // ---- coalesced epilogue: C -> wave-private LDS (bf16) -> 128B rows ----
  u16* tw = ((w < 2) ? As : Bs) + (w & 1) * 4096;
#pragma unroll
  for (int nt = 0; nt < 4; ++nt) {
    const int n = bn * 64 + nt * 16 + l15;
    float ba = 0.f, sc = 1.f;
    if (isQK) {
      if (bn < 16) { ba = bq[n] * QSCALE; sc = QSCALE; }
      else          ba = bk[n - 1024];
    }
#pragma unroll
    for (int mt = 0; mt < 4; ++mt)
#pragma unroll
      for (int r = 0; r < 4; ++r) {
        const int m = bm * 64 + mt * 16 + quad * 4 + r;
        const float v = isQK ? (acc[mt][nt][r] * sc + ba)
                             : (acc[mt][nt][r] + bv[m]);
        tw[(mt * 16 + quad * 4 + r) * 64 + nt * 16 + l15] = f2bf_fast(v);
      }
  }
  const int rr = lane >> 3, ch = lane & 7;   // 8 rows x 8 chunks of 16B
  if (isQK) {
    const bool isQ = (bn < 16);
    u16* op = isQ ? qw : kw;
    const int hh = isQ ? bn : bn - 16;
#pragma unroll
    for (int p = 0; p < 8; ++p) {
      const int row = p * 8 + rr;            // m_local
      const int m = bm * 64 + row;
      const int b = m >> 11, s = m & 2047;
      const uint4 val = *(const uint4*)&tw[row * 64 + ch * 8];
      *(uint4*)(op + ((size_t)((b * 16 + hh) * 2048 + s)) * 64 + ch * 8) = val;
    }
  } else {
    const int nb = bn * 64;
    const int b = nb >> 11, s = nb & 2047;   // wave's 64 seq cols, same b
#pragma unroll
    for (int p = 0; p < 8; ++p) {
      const int row = p * 8 + rr;            // m_local (dout)
      const int m = bm * 64 + row;
      const uint4 val = *(const uint4*)&tw[row * 64 + ch * 8];
      *(uint4*)(vw + ((size_t)(b * 1024 + m)) * 2048 + s + ch * 8) = val;
    }
  }
}

// ---------- flash attention: in-block K-split, 8 waves (R4 verified) ----------
// R11 XCD-chunked block remap: each XCD owns 4 heads x 16 q-tiles ->
// KV working set 2MB, L2-resident (FETCH 69.7 -> 12.3 MB measured).
// Block = 512 threads = waves (kh 0..1) x (qg 0..3). Wave (kh,qg) computes
// q-rows [qg*32,qg*32+32) over K-tiles [kh*16,kh*16+16). End: kh=1 pushes
// partial (ot,l) via LDS, kh=0 combines, normalizes, writes awp.
// LDS 80 KB -> 2 blocks/CU x 8 waves = 16 waves/CU (4/SIMD).
__global__ __launch_bounds__(512, 4) void attn_kernel(
    const u16* __restrict__ Q, const u16* __restrict__ Kt,
    const u16* __restrict__ Vt, u16* __restrict__ awp) {
  __shared__ __align__(16) u16 Sm[40960];  // 80 KB
  const int tid = threadIdx.x, lane = tid & 63, w = tid >> 6;  // w 0..7
  const int l31 = lane & 31, hi = lane >> 5, l7 = lane & 7;
  const int kh = w >> 2, qg = w & 3;

  // bijective XCD chunk: 512 blocks, 64 per XCD -> 4 heads per XCD
  const int bid = blockIdx.y * 16 + blockIdx.x;
  const int work = (bid & 7) * 64 + (bid >> 3);
  const int qt = work & 15;    // 0..15
  const int bh = work >> 4;    // 0..31

  const char* Qb = (const char*)(Q + ((size_t)bh * 2048 + qt * 128) * 64);
  const char* Kb = (const char*)(Kt + (size_t)bh * 2048 * 64);
  const char* Vb = (const char*)(Vt + (size_t)bh * 64 * 2048);

  // K/V buffers: Sm + (buf*2 + half)*8192 u16 (K tile 4096 u16, V next 4096)
  auto stageKV = [&](int j, int buf) {
#pragma unroll
    for (int h = 0; h < 2; ++h) {
      const int kt = h * 16 + j;
      u16* Kl = Sm + (buf * 2 + h) * 8192;
      u16* Vl = Kl + 4096;
      const int G = w * 64 + lane;     // 0..511
      const int r = G >> 3, sl = G & 7;
      gload_lds16(Kb + (size_t)(kt * 64 + r) * 128 + ((sl ^ (r & 7)) * 16),
                  &Kl[G * 8]);
      gload_lds16(Vb + (size_t)r * 4096 + kt * 128 + ((sl ^ (r & 7)) * 16),
                  &Vl[G * 8]);
    }
  };

  u16* Qs = Sm + 32768;  // 128 rows x 64 u16
#pragma unroll
  for (int i = 0; i < 2; ++i) {
    const int G = (w * 2 + i) * 64 + lane;   // 0..1023
    const int row = G >> 3, sl = G & 7;
    gload_lds16(Qb + (size_t)row * 128 + ((sl ^ (row & 7)) * 16), &Qs[G * 8]);
  }
  stageKV(0, 0);
  __syncthreads();

  // Q fragment (B-operand of 32x32x16): q = l31, d = ds*16 + hi*8 + j
  short8 aq[4];
#pragma unroll
  for (int ds = 0; ds < 4; ++ds)
    aq[ds] = *(const short8*)&Qs[(qg * 32 + l31) * 64 + (((ds << 1) + hi) ^ l7) * 8];
  // Qs is never overwritten during the loop -> no barrier needed here.

  f32x16 ot[2] = {};   // O^T acc: dt in {0,1}, d = dt*32 + (reg&3)+8*(reg>>2)+4*hi
  f32x2 l2 = {0.f, 0.f};

  for (int j = 0; j < 16; ++j) {
    const int buf = j & 1;
    if (j < 15) stageKV(j + 1, buf ^ 1);
    const u16* Kl = Sm + (buf * 2 + kh) * 8192;
    const u16* Vl = Kl + 4096;

#pragma unroll
    for (int t = 0; t < 2; ++t) {  // two 32-k S^T tiles per 64-k LDS tile
      f32x16 st = {};
      __builtin_amdgcn_s_setprio(1);
#pragma unroll
      for (int ds = 0; ds < 4; ++ds) {
        short8 kf = *(const short8*)&Kl[(t * 32 + l31) * 64 +
                                        (((ds << 1) + hi) ^ l7) * 8];
        st = mfma32(kf, aq[ds], st);
      }
      __builtin_amdgcn_s_setprio(0);
      float e[16];
#pragma unroll
      for (int i = 0; i < 16; ++i) e[i] = __builtin_amdgcn_exp2f(st[i]);
#pragma unroll
      for (int i = 0; i < 8; ++i) l2 += (f32x2){e[2 * i], e[2 * i + 1]};

      // pack to PV B-fragments: pairing (e0,e1)x(e4,e5) etc per T12
      uint32_t p01 = cvtpk(e[0], e[1]),   p23 = cvtpk(e[2], e[3]);
      uint32_t p45 = cvtpk(e[4], e[5]),   p67 = cvtpk(e[6], e[7]);
      uint32_t p89 = cvtpk(e[8], e[9]),   pAB = cvtpk(e[10], e[11]);
      uint32_t pCD = cvtpk(e[12], e[13]), pEF = cvtpk(e[14], e[15]);
      permswap(p01, p45);  // -> ksub0 w0, w2
      permswap(p23, p67);  // -> ksub0 w1, w3
      permswap(p89, pCD);  // -> ksub1 w0, w2
      permswap(pAB, pEF);  // -> ksub1 w1, w3
      union { uint32_t u[4]; short8 s; } b0, b1;
      b0.u[0] = p01; b0.u[1] = p23; b0.u[2] = p45; b0.u[3] = p67;
      b1.u[0] = p89; b1.u[1] = pAB; b1.u[2] = pCD; b1.u[3] = pEF;

      __builtin_amdgcn_s_setprio(1);
#pragma unroll
      for (int dt = 0; dt < 2; ++dt) {
#pragma unroll
        for (int s2 = 0; s2 < 2; ++s2) {
          short8 vf = *(const short8*)&Vl[(dt * 32 + l31) * 64 +
                                          ((((t * 2 + s2) << 1) + hi) ^ l7) * 8];
          ot[dt] = mfma32(vf, s2 ? b1.s : b0.s, ot[dt]);
        }
      }
      __builtin_amdgcn_s_setprio(0);
    }
    if (j < 15) __syncthreads();
  }

  // l partial for this wave's kt-range, per q=l31
  float l = l2.x + l2.y;
  l += __shfl_xor(l, 32);

  // ---- in-block combine: kh=1 -> LDS -> kh=0 adds, normalizes, writes ----
  __syncthreads();   // all compute done before reusing Sm
  float* fb = (float*)Sm;  // slot per (qg,lane): 34 floats, b64 stride-34
  if (kh == 1) {
    float* p = fb + (qg * 64 + lane) * 34;
#pragma unroll
    for (int i = 0; i < 8; ++i) {
      *(f32x2*)(p + 2 * i)      = (f32x2){ot[0][2 * i], ot[0][2 * i + 1]};
      *(f32x2*)(p + 16 + 2 * i) = (f32x2){ot[1][2 * i], ot[1][2 * i + 1]};
    }
    p[32] = l;
  }
  __syncthreads();
  if (kh == 0) {
    const float* p = fb + (qg * 64 + lane) * 34;
#pragma unroll
    for (int i = 0; i < 16; ++i) ot[0][i] += p[i];
#pragma unroll
    for (int i = 0; i < 16; ++i) ot[1][i] += p[16 + i];
    l += p[32];
    const float inv = __builtin_amdgcn_rcpf(l);

    const int b = bh >> 4, h = bh & 15;
    const int rt = b * 128 + qt * 8 + qg * 2 + (l31 >> 4);  // row = rt*16+(lane&15)
#pragma unroll
    for (int dt = 0; dt < 2; ++dt) {
      const int kc = h * 2 + dt;
#pragma unroll
      for (int g = 0; g < 4; ++g) {  // reg group: d = dt*32+(reg&3)+8*g+4*hi
        const int ln = (lane & 15) + 16 * g;
        uint2 ov;
        ov.x = cvtpk(ot[dt][4 * g + 0] * inv, ot[dt][4 * g + 1] * inv);
        ov.y = cvtpk(ot[dt][4 * g + 2] * inv, ot[dt][4 * g + 3] * inv);
        *(uint2*)(awp + ((size_t)((rt * 32 + kc) * 64 + ln)) * 8 + hi * 4) = ov;
      }
    }
  }
}

// ---------- out projection v2: 128x64 tiles, grid 512, min-2-phase ----------
// C[4096,1024] f32 = aw @ Wo^T + bo. Was 256 blocks = 1 block/CU (2 waves/
// SIMD latency exposure). Now 512 blocks x 512 threads (8 waves of 32x32),
// BK=64/stage (3 gloads/thread), LDS 48KB -> 2 blocks/CU = 16 waves/CU.
__global__ __launch_bounds__(512) void out_proj(const u16* __restrict__ awp,
                                                const u16* __restrict__ wp,
                                                const float* __restrict__ bo,
                                                float* __restrict__ out) {
  __shared__ __align__(16) u16 As[16384];  // 2 bufs x (2 kc x 8 tiles x 512)
  __shared__ __align__(16) u16 Bs[8192];   // 2 bufs x (2 kc x 4 tiles x 512)
  const int tid = threadIdx.x, lane = tid & 63, w = tid >> 6;  // w 0..7
  const int quad = lane >> 4, l15 = lane & 15;

  const int bid = blockIdx.x;                    // 0..511
  const int work = (bid & 7) * 64 + (bid >> 3);  // bijective XCD chunk
  const int bm2 = work >> 4, bn2 = work & 15;    // 32 x 16 grid
  const int at0 = bm2 * 8, bt0 = 192 + bn2 * 4;  // Wo = wp tiles 192..255
  const int wr = w >> 1, wc = w & 1;             // wave tile 32x32

  // stage BK=64 (kc pair 2ks,2ks+1): A 16 slices, B 8 slices; 3/thread.
  // (i=0,1): A kc=2ks+i, tile=w.  (i=2): B kc=2ks+(w>>2), tile=w&3.
  auto stage = [&](int ks, int buf) {
    const int kc0 = ks * 2;
#pragma unroll
    for (int i = 0; i < 2; ++i) {
      const u16* src = awp + (((at0 + w) << 5) + kc0 + i) * 512 + lane * 8;
      u16* dst = As + buf * 8192 + (i * 8 + w) * 512 + lane * 8;
      gload_lds16(src, dst);
    }
    {
      const int c = w >> 2, tg = w & 3;
      const u16* src = wp + (((bt0 + tg) << 5) + kc0 + c) * 512 + lane * 8;
      u16* dst = Bs + buf * 4096 + (c * 4 + tg) * 512 + lane * 8;
      gload_lds16(src, dst);
    }
  };

  f32x4 acc[2][2] = {};

  stage(0, 0);
  __syncthreads();

  for (int ks = 0; ks < 16; ++ks) {
    const int cur = ks & 1;
    if (ks < 15) stage(ks + 1, cur ^ 1);

    const u16* Ab = As + cur * 8192;
    const u16* Bb = Bs + cur * 4096;
#pragma unroll
    for (int c = 0; c < 2; ++c) {
      short8 af[2], bf[2];
#pragma unroll
      for (int mt = 0; mt < 2; ++mt)
        af[mt] = *(const short8*)&Ab[((c * 8 + wr * 2 + mt) * 64 + lane) * 8];
#pragma unroll
      for (int nt = 0; nt < 2; ++nt)
        bf[nt] = *(const short8*)&Bb[((c * 4 + wc * 2 + nt) * 64 + lane) * 8];
#pragma unroll
      for (int mt = 0; mt < 2; ++mt)
#pragma unroll
        for (int nt = 0; nt < 2; ++nt)
          acc[mt][nt] = mfma16(af[mt], bf[nt], acc[mt][nt]);
    }
    __syncthreads();
  }

#pragma unroll
  for (int nt = 0; nt < 2; ++nt) {
    const int n = bn2 * 64 + wc * 32 + nt * 16 + l15;
    const float bb = bo[n];
#pragma unroll
    for (int mt = 0; mt < 2; ++mt)
#pragma unroll
      for (int r = 0; r < 4; ++r) {
        const int m = bm2 * 128 + wr * 32 + mt * 16 + quad * 4 + r;
        out[(size_t)m * 1024 + n] = acc[mt][nt][r] + bb;
      }
  }
}

// ---------- launch ----------
extern "C" void kernel_launch(void* const* d_in, const int* in_sizes, int n_in,
                              void* d_out, int out_size, void* d_ws, size_t ws_size,
                              hipStream_t stream) {
  const float* x  = (const float*)d_in[0];
  const float* Wq = (const float*)d_in[1];
  const float* bq = (const float*)d_in[2];
  const float* Wk = (const float*)d_in[3];
  const float* bk = (const float*)d_in[4];
  const float* Wv = (const float*)d_in[5];
  const float* bv = (const float*)d_in[6];
  const float* Wo = (const float*)d_in[7];
  const float* bo = (const float*)d_in[8];

  const size_t M4 = (size_t)4 * 1024 * 1024;
  u16* xp  = (u16*)d_ws;
  u16* wp  = xp + M4;        // packed [Wq;Wk;Wv;Wo]
  u16* qw  = wp + M4;
  u16* kw  = qw + M4;
  u16* vw  = kw + M4;
  u16* awp = vw + M4;

  pack_all<<<4096, 256, 0, stream>>>(x, Wq, Wk, Wv, Wo, xp, wp);

  proj_qkv<<<768, 256, 0, stream>>>(xp, wp, bq, bk, bv, qw, kw, vw);

  attn_kernel<<<dim3(16, 32), 512, 0, stream>>>(qw, kw, vw, awp);

  out_proj<<<512, 512, 0, stream>>>(awp, wp, bo, (float*)d_out);
}